// Round 1
// baseline (341.102 us; speedup 1.0000x reference)
//
#include <hip/hip_runtime.h>

// GraphConv: out[n, 0:32]  = relu(features[n] @ W)
//            out[n, 32:64] = relu(mean_{e: src=n}(features[tgt[e]]) @ W)
// Uses linearity: mean(features)@W == mean(features@W), so we compute
// XW = features@W once and scatter-mean XW.
//
// ws layout: msum[N*32] f32 accumulators, then cnt[N] int32.
// out left halves (raw XW) double as the gather source for the scatter
// kernel; ReLU is applied in the finalize pass.

__global__ __launch_bounds__(256) void xw_kernel(
    const float* __restrict__ feat, const float* __restrict__ W,
    float* __restrict__ out, int N) {
    __shared__ float Ws[32 * 32];
    int t = threadIdx.x;
    for (int i = t; i < 1024; i += 256) Ws[i] = W[i];
    __syncthreads();
    int node = blockIdx.x * 8 + (t >> 5);
    int j = t & 31;
    if (node >= N) return;
    float fj = feat[node * 32 + j];
    float acc = 0.f;
#pragma unroll
    for (int k = 0; k < 32; ++k) {
        acc += __shfl(fj, k, 32) * Ws[k * 32 + j];
    }
    // raw (pre-ReLU) XW into left half of out; finalize applies ReLU
    out[node * 64 + j] = acc;
}

__global__ __launch_bounds__(256) void scatter_kernel(
    const int* __restrict__ esrc, const int* __restrict__ etgt,
    const float* __restrict__ xw /* = out, stride 64, left half */,
    float* __restrict__ msum, int* __restrict__ cnt, int E) {
    int tid = blockIdx.x * 256 + threadIdx.x;  // E*32 = 51.2M < 2^31
    int e = tid >> 5;
    int j = tid & 31;
    if (e >= E) return;
    int s = esrc[e];
    int t = etgt[e];
    float v = xw[(size_t)t * 64 + j];  // 32 lanes -> contiguous 128B
    atomicAdd(&msum[(size_t)s * 32 + j], v);
    if (j == 0) atomicAdd(&cnt[s], 1);
}

__global__ __launch_bounds__(256) void finalize_kernel(
    const float* __restrict__ msum, const int* __restrict__ cnt,
    float* __restrict__ out, int N) {
    int tid = blockIdx.x * 256 + threadIdx.x;
    int n = tid >> 5;
    int j = tid & 31;
    if (n >= N) return;
    float c = (float)(cnt[n] > 1 ? cnt[n] : 1);
    float m = msum[(size_t)n * 32 + j] / c;
    out[(size_t)n * 64 + 32 + j] = fmaxf(m, 0.f);
    float x = out[(size_t)n * 64 + j];
    out[(size_t)n * 64 + j] = fmaxf(x, 0.f);
}

extern "C" void kernel_launch(void* const* d_in, const int* in_sizes, int n_in,
                              void* d_out, int out_size, void* d_ws, size_t ws_size,
                              hipStream_t stream) {
    const float* feat = (const float*)d_in[0];
    const float* W    = (const float*)d_in[1];
    const int* esrc   = (const int*)d_in[2];
    const int* etgt   = (const int*)d_in[3];
    // d_in[4] = num_nodes scalar; derive from sizes instead.
    int N = in_sizes[0] / 32;
    int E = in_sizes[2];
    float* out  = (float*)d_out;
    float* msum = (float*)d_ws;
    int*   cnt  = (int*)((char*)d_ws + (size_t)N * 32 * sizeof(float));

    // zero accumulators (msum + cnt = N*33 words)
    hipMemsetAsync(d_ws, 0, (size_t)N * 33 * sizeof(float), stream);

    xw_kernel<<<(N + 7) / 8, 256, 0, stream>>>(feat, W, out, N);

    int threads2 = E * 32;
    scatter_kernel<<<(threads2 + 255) / 256, 256, 0, stream>>>(
        esrc, etgt, out, msum, cnt, E);

    finalize_kernel<<<(N * 32 + 255) / 256, 256, 0, stream>>>(msum, cnt, out, N);
}

// Round 2
// 339.984 us; speedup vs baseline: 1.0033x; 1.0033x over previous
//
#include <hip/hip_runtime.h>

// GraphConv via CSR counting-sort (no float atomics):
//   out[n, 0:32]  = relu(XW[n]),            XW = features @ W
//   out[n, 32:64] = relu(mean_{e:src=n} XW[tgt[e]])   (linearity of mean)
//
// Pipeline: [memset cnt] -> xw+hist -> blocksum -> scan_partials ->
//           scan_offsets -> bucket (counting-sort edges) -> gather-sum
// ws layout: cnt[N] | offs[N] | partials[Ppad] | blockoffs[Ppad] |
//            sorted[E] | (optional, if ws_size allows) xw[N*32] f32

__global__ __launch_bounds__(256) void xw_hist_kernel(
    const float* __restrict__ feat, const float* __restrict__ W,
    const int* __restrict__ esrc, int* __restrict__ cnt, int E,
    float* __restrict__ xw, int xs, float* __restrict__ out, int write_relu,
    int N) {
    __shared__ float Ws[32 * 32];
    int t = threadIdx.x;
    for (int i = t; i < 1024; i += 256) Ws[i] = W[i];
    // edge histogram (independent of LDS)
    int eid = blockIdx.x * 256 + t;
    if (eid < E) atomicAdd(&cnt[esrc[eid]], 1);
    __syncthreads();
    int node = blockIdx.x * 8 + (t >> 5);
    int j = t & 31;
    if (node >= N) return;
    float fj = feat[(size_t)node * 32 + j];
    float acc = 0.f;
#pragma unroll
    for (int k = 0; k < 32; ++k)
        acc += __shfl(fj, k, 32) * Ws[k * 32 + j];
    xw[(size_t)node * xs + j] = acc;                       // raw (gather source)
    if (write_relu) out[(size_t)node * 64 + j] = fmaxf(acc, 0.f);
}

__global__ __launch_bounds__(256) void blocksum_kernel(
    const int* __restrict__ cnt, int* __restrict__ partials, int N) {
    int i = blockIdx.x * 256 + threadIdx.x;
    int v = (i < N) ? cnt[i] : 0;
#pragma unroll
    for (int off = 32; off > 0; off >>= 1) v += __shfl_down(v, off, 64);
    __shared__ int s[4];
    if ((threadIdx.x & 63) == 0) s[threadIdx.x >> 6] = v;
    __syncthreads();
    if (threadIdx.x == 0) partials[blockIdx.x] = s[0] + s[1] + s[2] + s[3];
}

// exclusive scan of P (<=1024) partials in one block
__global__ __launch_bounds__(1024) void scan_partials_kernel(
    const int* __restrict__ partials, int* __restrict__ blockoffs, int P) {
    __shared__ int s[1024];
    int t = threadIdx.x;
    int v = (t < P) ? partials[t] : 0;
    s[t] = v;
    __syncthreads();
    for (int off = 1; off < 1024; off <<= 1) {
        int x = (t >= off) ? s[t - off] : 0;
        __syncthreads();
        s[t] += x;
        __syncthreads();
    }
    if (t < P) blockoffs[t] = s[t] - v;  // exclusive
}

__global__ __launch_bounds__(256) void scan_offsets_kernel(
    const int* __restrict__ cnt, const int* __restrict__ blockoffs,
    int* __restrict__ offs, int N) {
    __shared__ int s[256];
    int t = threadIdx.x;
    int i = blockIdx.x * 256 + t;
    int v = (i < N) ? cnt[i] : 0;
    s[t] = v;
    __syncthreads();
    for (int off = 1; off < 256; off <<= 1) {
        int x = (t >= off) ? s[t - off] : 0;
        __syncthreads();
        s[t] += x;
        __syncthreads();
    }
    if (i < N) offs[i] = s[t] - v + blockoffs[blockIdx.x];
}

// counting-sort edges by src; offs[n] ends up = segment end
__global__ __launch_bounds__(256) void bucket_kernel(
    const int* __restrict__ esrc, const int* __restrict__ etgt,
    int* __restrict__ offs, int* __restrict__ sorted, int E) {
    int e = blockIdx.x * 256 + threadIdx.x;
    if (e >= E) return;
    int s = esrc[e];
    int pos = atomicAdd(&offs[s], 1);
    sorted[pos] = etgt[e];
}

// 32 lanes per node: cooperative index load + shfl broadcast, reg accumulate
__global__ __launch_bounds__(256) void gather_kernel(
    const int* __restrict__ offs, const int* __restrict__ cnt,
    const int* __restrict__ sorted, const float* __restrict__ xw, int xs,
    float* __restrict__ out, int N) {
    int g = blockIdx.x * 8 + (threadIdx.x >> 5);
    int j = threadIdx.x & 31;
    if (g >= N) return;
    int c = cnt[g];
    int end = offs[g];          // post-bucket: start + c
    int start = end - c;
    float acc = 0.f;
    for (int base = start; base < end; base += 32) {
        int idx = base + j;
        int t_l = (idx < end) ? sorted[idx] : 0;
        int m = end - base; if (m > 32) m = 32;
        for (int k = 0; k < m; ++k) {
            int tt = __shfl(t_l, k, 32);
            acc += xw[(size_t)tt * xs + j];
        }
    }
    float denom = (float)(c > 1 ? c : 1);
    out[(size_t)g * 64 + 32 + j] = fmaxf(acc / denom, 0.f);
}

__global__ __launch_bounds__(256) void relu_left_kernel(
    float* __restrict__ out, int N) {
    int i = blockIdx.x * 256 + threadIdx.x;
    if (i >= N * 32) return;
    int n = i >> 5, j = i & 31;
    float x = out[(size_t)n * 64 + j];
    out[(size_t)n * 64 + j] = fmaxf(x, 0.f);
}

extern "C" void kernel_launch(void* const* d_in, const int* in_sizes, int n_in,
                              void* d_out, int out_size, void* d_ws, size_t ws_size,
                              hipStream_t stream) {
    const float* feat = (const float*)d_in[0];
    const float* W    = (const float*)d_in[1];
    const int* esrc   = (const int*)d_in[2];
    const int* etgt   = (const int*)d_in[3];
    int N = in_sizes[0] / 32;
    int E = in_sizes[2];
    float* out = (float*)d_out;
    char* ws = (char*)d_ws;

    int P = (N + 255) / 256;           // scan blocks (391 for N=100k, <=1024)
    int Ppad = (P + 63) & ~63;
    int* cnt       = (int*)ws;
    int* offs      = cnt + N;
    int* partials  = offs + N;
    int* blockoffs = partials + Ppad;
    int* sorted    = blockoffs + Ppad;
    size_t sorted_end = (size_t)((char*)(sorted + E) - ws);
    size_t xw_off = (sorted_end + 255) & ~(size_t)255;
    size_t need_compact = xw_off + (size_t)N * 32 * sizeof(float);
    bool compact = (ws_size >= need_compact);
    float* xw = compact ? (float*)(ws + xw_off) : out;
    int xs = compact ? 32 : 64;

    hipMemsetAsync(cnt, 0, (size_t)N * sizeof(int), stream);

    int nb1 = (N + 7) / 8;
    int nbe = (E + 255) / 256;
    int nb1h = nb1 > nbe ? nb1 : nbe;   // cover both nodes and edges
    xw_hist_kernel<<<nb1h, 256, 0, stream>>>(feat, W, esrc, cnt, E,
                                             xw, xs, out, compact ? 1 : 0, N);
    blocksum_kernel<<<P, 256, 0, stream>>>(cnt, partials, N);
    scan_partials_kernel<<<1, 1024, 0, stream>>>(partials, blockoffs, P);
    scan_offsets_kernel<<<P, 256, 0, stream>>>(cnt, blockoffs, offs, N);
    bucket_kernel<<<nbe, 256, 0, stream>>>(esrc, etgt, offs, sorted, E);
    gather_kernel<<<nb1, 256, 0, stream>>>(offs, cnt, sorted, xw, xs, out, N);
    if (!compact)
        relu_left_kernel<<<(N * 32 + 255) / 256, 256, 0, stream>>>(out, N);
}